// Round 3
// baseline (334.798 us; speedup 1.0000x reference)
//
#include <hip/hip_runtime.h>

// Multi-hot encode: out[n, t, x[n, t, f]] = 1.0, everything else 0.
// x: [32, 512, 10] int32, out: [32, 512, 5000] fp32 (~328 MB written/call).
//
// R3 (= R2 with compile fix): single-pass compare-based fill. One block per
// (n,t) row; the row's 10 indices are block-uniform (SGPRs). Each lane
// computes 4 output elements per 16B store as (pos == idx[j]) ? 1 : 0 — no
// zero-then-scatter, no __syncthreads/vmcnt(0) drain, every cache line
// written exactly once. Nontemporal stores: output is never re-read.
//
// Fix vs R2: __builtin_nontemporal_store needs a native clang vector type,
// not HIP's float4 struct -> use ext_vector_type(4).

#define NUM_TOKENS 5000
#define NFEAT 10

typedef float vfloat4 __attribute__((ext_vector_type(4)));

__global__ __launch_bounds__(256) void tenhot_kernel(const int* __restrict__ x,
                                                     float* __restrict__ out) {
    const int row = blockIdx.x;  // n*T + t, 0..16383

    // Block-uniform: compiler lifts these to scalar loads/SGPRs.
    int idx[NFEAT];
#pragma unroll
    for (int j = 0; j < NFEAT; ++j) idx[j] = x[row * NFEAT + j];

    vfloat4* __restrict__ row4 =
        reinterpret_cast<vfloat4*>(out + (size_t)row * NUM_TOKENS);

    // 5000 floats = 1250 vfloat4 (20000 B row stride, 16 B aligned).
    for (int i = threadIdx.x; i < NUM_TOKENS / 4; i += 256) {
        const int p = i * 4;
        vfloat4 val;
#pragma unroll
        for (int c = 0; c < 4; ++c) {
            float v = 0.0f;
#pragma unroll
            for (int j = 0; j < NFEAT; ++j) {
                v = (p + c == idx[j]) ? 1.0f : v;  // branch-free select chain
            }
            val[c] = v;
        }
        __builtin_nontemporal_store(val, &row4[i]);
    }
}

extern "C" void kernel_launch(void* const* d_in, const int* in_sizes, int n_in,
                              void* d_out, int out_size, void* d_ws, size_t ws_size,
                              hipStream_t stream) {
    const int* x = (const int*)d_in[0];
    float* out = (float*)d_out;
    const int n_rows = in_sizes[0] / NFEAT;  // 32*512 = 16384
    tenhot_kernel<<<n_rows, 256, 0, stream>>>(x, out);
}

// Round 4
// 329.131 us; speedup vs baseline: 1.0172x; 1.0172x over previous
//
#include <hip/hip_runtime.h>

// Multi-hot encode: out[n, t, x[n, t, f]] = 1.0, everything else 0.
// x: [32, 512, 10] int32, out: [32, 512, 5000] fp32 (~328 MB written/call).
//
// R4: LDS-staged row build. R3's compare-fill was VALU-bound (~80 v_cmp/
// v_cndmask per 16B store -> ~3.9 TB/s ceiling). Instead: build the row in
// LDS (zero + scatter 10 ones), barrier (cheap: only lgkmcnt outstanding,
// no global-store vmcnt drain like R1), then stream LDS -> global with
// ds_read_b128 + nontemporal dwordx4 stores (~6 inst per 16B).
// LDS 20000 B/block -> 8 blocks/CU -> 32 waves/CU (full occupancy).

#define NUM_TOKENS 5000
#define NFEAT 10
#define NCHUNK (NUM_TOKENS / 4)  // 1250 float4 chunks per row

typedef float vfloat4 __attribute__((ext_vector_type(4)));

__global__ __launch_bounds__(256) void tenhot_kernel(const int* __restrict__ x,
                                                     float* __restrict__ out) {
    __shared__ vfloat4 row_lds[NCHUNK];  // 20000 B

    const int row = blockIdx.x;  // n*T + t, 0..16383
    const int tid = threadIdx.x;

    // Phase A: zero the LDS row image (ds_write_b128, ~5 per lane).
    const vfloat4 z = {0.f, 0.f, 0.f, 0.f};
#pragma unroll
    for (int i = tid; i < NCHUNK; i += 256) {
        row_lds[i] = z;
    }

    __syncthreads();  // only LDS writes outstanding -> lgkmcnt wait, fast

    // Phase B: scatter the 10 ones into LDS.
    if (tid < NFEAT) {
        const int idx = x[row * NFEAT + tid];
        reinterpret_cast<float*>(row_lds)[idx] = 1.0f;
    }

    __syncthreads();  // again lgkmcnt-only

    // Phase C: stream LDS -> global, 16 B per store, every line written once.
    vfloat4* __restrict__ row4 =
        reinterpret_cast<vfloat4*>(out + (size_t)row * NUM_TOKENS);
#pragma unroll
    for (int i = tid; i < NCHUNK; i += 256) {
        __builtin_nontemporal_store(row_lds[i], &row4[i]);
    }
}

extern "C" void kernel_launch(void* const* d_in, const int* in_sizes, int n_in,
                              void* d_out, int out_size, void* d_ws, size_t ws_size,
                              hipStream_t stream) {
    const int* x = (const int*)d_in[0];
    float* out = (float*)d_out;
    const int n_rows = in_sizes[0] / NFEAT;  // 32*512 = 16384
    tenhot_kernel<<<n_rows, 256, 0, stream>>>(x, out);
}